// Round 1
// baseline (1894.671 us; speedup 1.0000x reference)
//
#include <hip/hip_runtime.h>
#include <math.h>

// Problem dims (fixed by setup_inputs): B=4, C=384, H=W=Y=X=64, n_div=12,
// n_head=1, hd=32. P = H*W = 4096 pixels.
#define B_   4
#define C_   384
#define HD_  32
#define P_   4096   // 64*64
#define SCALE_ 0.17677669529663687f  // 1/sqrt(32)

// out[b,d,p] = sum_c W[d,c] * in[b,c,p]
__global__ void proj_kernel(const float* __restrict__ W,
                            const float* __restrict__ in,
                            float* __restrict__ out, int D) {
    int idx = blockIdx.x * 256 + threadIdx.x;
    int total = B_ * D * P_;
    if (idx >= total) return;
    int p = idx & (P_ - 1);
    int d = (idx >> 12) % D;
    int b = idx / (D * P_);
    const float* ib = in + (size_t)b * C_ * P_ + p;
    const float* wr = W + (size_t)d * C_;
    float acc = 0.f;
    #pragma unroll 8
    for (int c = 0; c < C_; ++c) acc += wr[c] * ib[(size_t)c * P_];
    out[idx] = acc;
}

// One block (256 threads) per (b, query-pixel hw).
// q: [B,32,P], kv: [B,64,P] (k = rows 0..31, v = rows 32..63), o: [B,32,P]
__global__ void attn_kernel(const float* __restrict__ q,
                            const float* __restrict__ kv,
                            float* __restrict__ o) {
    __shared__ float s[P_];
    __shared__ float qs[HD_];
    __shared__ float red[256];
    int bhw = blockIdx.x;
    int b = bhw >> 12;
    int hw = bhw & (P_ - 1);
    int t = threadIdx.x;

    if (t < HD_) qs[t] = q[((size_t)b * HD_ + t) * P_ + hw];
    __syncthreads();

    const float* kb = kv + (size_t)b * 2 * HD_ * P_;
    float lmax = -INFINITY;
    for (int yx = t; yx < P_; yx += 256) {
        float acc = 0.f;
        #pragma unroll
        for (int c = 0; c < HD_; ++c) acc += qs[c] * kb[(size_t)c * P_ + yx];
        acc *= SCALE_;
        s[yx] = acc;
        lmax = fmaxf(lmax, acc);
    }
    red[t] = lmax; __syncthreads();
    for (int off = 128; off > 0; off >>= 1) {
        if (t < off) red[t] = fmaxf(red[t], red[t + off]);
        __syncthreads();
    }
    float m = red[0]; __syncthreads();

    float lsum = 0.f;
    for (int yx = t; yx < P_; yx += 256) {
        float e = __expf(s[yx] - m);
        s[yx] = e;
        lsum += e;
    }
    red[t] = lsum; __syncthreads();
    for (int off = 128; off > 0; off >>= 1) {
        if (t < off) red[t] += red[t + off];
        __syncthreads();
    }
    float inv = 1.0f / red[0];
    __syncthreads();

    // PV: thread t handles c = t&31, key chunk = t>>5 (8 chunks of 512)
    int c = t & 31, chunk = t >> 5;
    const float* vb = kv + ((size_t)b * 2 * HD_ + HD_) * P_;
    float acc = 0.f;
    const float* vr = vb + (size_t)c * P_ + chunk * 512;
    const float* sr = s + chunk * 512;
    #pragma unroll 8
    for (int i = 0; i < 512; ++i) acc += sr[i] * vr[i];
    red[t] = acc; __syncthreads();
    if (t < HD_) {
        float sum = 0.f;
        #pragma unroll
        for (int i = 0; i < 8; ++i) sum += red[t + 32 * i];
        o[((size_t)b * HD_ + t) * P_ + hw] = sum * inv;
    }
}

// 3x3 conv (C_ out <- HD_ in), SAME padding, + bias + residual x
__global__ void conv_res_kernel(const float* __restrict__ ao,
                                const float* __restrict__ Wout,
                                const float* __restrict__ bout,
                                const float* __restrict__ x,
                                float* __restrict__ out) {
    int idx = blockIdx.x * 256 + threadIdx.x;
    const int total = B_ * C_ * P_;
    if (idx >= total) return;
    int w = idx & 63;
    int h = (idx >> 6) & 63;
    int co = (idx >> 12) % C_;
    int b = idx / (C_ * P_);
    float acc = bout[co];
    const float* wbase = Wout + (size_t)co * HD_ * 9;
    const float* abase = ao + (size_t)b * HD_ * P_;
    for (int ci = 0; ci < HD_; ++ci) {
        const float* wr = wbase + ci * 9;
        const float* ar = abase + (size_t)ci * P_;
        #pragma unroll
        for (int ky = 0; ky < 3; ++ky) {
            int y = h + ky - 1;
            if ((unsigned)y >= 64u) continue;
            #pragma unroll
            for (int kx = 0; kx < 3; ++kx) {
                int xw = w + kx - 1;
                if ((unsigned)xw >= 64u) continue;
                acc += wr[ky * 3 + kx] * ar[(y << 6) + xw];
            }
        }
    }
    out[idx] = acc + x[idx];
}

extern "C" void kernel_launch(void* const* d_in, const int* in_sizes, int n_in,
                              void* d_out, int out_size, void* d_ws, size_t ws_size,
                              hipStream_t stream) {
    const float* x    = (const float*)d_in[0];
    const float* xe   = (const float*)d_in[1];
    const float* Wq   = (const float*)d_in[2];
    const float* Wkv  = (const float*)d_in[3];
    const float* Wout = (const float*)d_in[4];
    const float* bout = (const float*)d_in[5];
    float* out = (float*)d_out;

    float* ws = (float*)d_ws;
    float* q  = ws;                         // B*32*P = 524288
    float* kv = q + (size_t)B_ * HD_ * P_;  // B*64*P = 1048576
    float* ao = kv + (size_t)B_ * 2 * HD_ * P_; // B*32*P = 524288

    {   // q projection: B*32*P threads
        int total = B_ * HD_ * P_;
        proj_kernel<<<(total + 255) / 256, 256, 0, stream>>>(Wq, x, q, HD_);
    }
    {   // kv projection: B*64*P threads
        int total = B_ * 2 * HD_ * P_;
        proj_kernel<<<(total + 255) / 256, 256, 0, stream>>>(Wkv, xe, kv, 2 * HD_);
    }
    attn_kernel<<<B_ * P_, 256, 0, stream>>>(q, kv, ao);
    {
        int total = B_ * C_ * P_;
        conv_res_kernel<<<(total + 255) / 256, 256, 0, stream>>>(ao, Wout, bout, x, out);
    }
}

// Round 2
// 613.057 us; speedup vs baseline: 3.0905x; 3.0905x over previous
//
#include <hip/hip_runtime.h>
#include <hip/hip_bf16.h>
#include <math.h>

// B=4, C=384, H=W=Y=X=64, n_head=1, hd=32, P=4096
#define B_   4
#define C_   384
#define HD_  32
#define P_   4096
#define SCALE_ 0.17677669529663687f  // 1/sqrt(32)

typedef __attribute__((ext_vector_type(4))) float f32x4;
typedef __attribute__((ext_vector_type(8))) short short8;

static __device__ inline unsigned pk_bf16(float a, float b) {
    __hip_bfloat16 x = __float2bfloat16(a), y = __float2bfloat16(b);
    unsigned short ux = *reinterpret_cast<unsigned short*>(&x);
    unsigned short uy = *reinterpret_cast<unsigned short*>(&y);
    return (unsigned)ux | ((unsigned)uy << 16);
}
static __device__ inline short bf16_bits(float a) {
    __hip_bfloat16 x = __float2bfloat16(a);
    return *reinterpret_cast<short*>(&x);
}

// ---- Q projection: qT[b][p][32] bf16 = Wq[32][384] . x[b][384][p]
__global__ void proj_q_kernel(const float* __restrict__ Wq,
                              const float* __restrict__ x,
                              short* __restrict__ qT) {
    __shared__ float xs[64][64];   // c-chunk x p
    __shared__ float ws[32][64];   // d x c-chunk
    int b  = blockIdx.x >> 6;
    int p0 = (blockIdx.x & 63) << 6;
    int t = threadIdx.x;
    int p = t & 63, dg = t >> 6;   // dg 0..3 -> d = dg*8+j
    float acc[8] = {0,0,0,0,0,0,0,0};
    for (int c0 = 0; c0 < C_; c0 += 64) {
        __syncthreads();
        #pragma unroll
        for (int i = 0; i < 16; ++i) {
            int row = (t >> 6) + i * 4;
            xs[row][p] = x[((size_t)b * C_ + c0 + row) * P_ + p0 + p];
        }
        #pragma unroll
        for (int i = 0; i < 8; ++i) {
            int idx = t + i * 256;
            int d = idx >> 6, cc = idx & 63;
            ws[d][cc] = Wq[(size_t)d * C_ + c0 + cc];
        }
        __syncthreads();
        for (int cc = 0; cc < 64; ++cc) {
            float xv = xs[cc][p];
            #pragma unroll
            for (int j = 0; j < 8; ++j) acc[j] += ws[dg * 8 + j][cc] * xv;
        }
    }
    unsigned* outp = (unsigned*)(qT + ((size_t)b * P_ + p0 + p) * HD_ + dg * 8);
    #pragma unroll
    for (int j = 0; j < 4; ++j) outp[j] = pk_bf16(acc[2 * j], acc[2 * j + 1]);
}

// ---- KV projection: kT[b][p][32] bf16 (d 0..31), vT[b][32][p] bf16 (d 32..63)
__global__ void proj_kv_kernel(const float* __restrict__ Wkv,
                               const float* __restrict__ xe,
                               short* __restrict__ kT,
                               short* __restrict__ vT) {
    __shared__ float xs[64][64];
    __shared__ float ws[64][64];
    int b  = blockIdx.x >> 6;
    int p0 = (blockIdx.x & 63) << 6;
    int t = threadIdx.x;
    int p = t & 63, dg = t >> 6;   // dg 0..3 -> d = dg*16+j
    float acc[16];
    #pragma unroll
    for (int j = 0; j < 16; ++j) acc[j] = 0.f;
    for (int c0 = 0; c0 < C_; c0 += 64) {
        __syncthreads();
        #pragma unroll
        for (int i = 0; i < 16; ++i) {
            int row = (t >> 6) + i * 4;
            xs[row][p] = xe[((size_t)b * C_ + c0 + row) * P_ + p0 + p];
        }
        #pragma unroll
        for (int i = 0; i < 16; ++i) {
            int idx = t + i * 256;
            int d = idx >> 6, cc = idx & 63;
            ws[d][cc] = Wkv[(size_t)d * C_ + c0 + cc];
        }
        __syncthreads();
        for (int cc = 0; cc < 64; ++cc) {
            float xv = xs[cc][p];
            #pragma unroll
            for (int j = 0; j < 16; ++j) acc[j] += ws[dg * 16 + j][cc] * xv;
        }
    }
    if (dg < 2) {
        unsigned* outp = (unsigned*)(kT + ((size_t)b * P_ + p0 + p) * HD_ + dg * 16);
        #pragma unroll
        for (int j = 0; j < 8; ++j) outp[j] = pk_bf16(acc[2 * j], acc[2 * j + 1]);
    } else {
        #pragma unroll
        for (int j = 0; j < 16; ++j) {
            int d = (dg - 2) * 16 + j;
            vT[((size_t)b * HD_ + d) * P_ + p0 + p] = bf16_bits(acc[j]);
        }
    }
}

// ---- Flash attention, MFMA. Grid: B*(P/16) blocks, 256 threads (4 waves).
// Wave w handles keys [w*1024, w*1024+1024); flash-combine at the end.
// S^T = mfma(K, Q); O^T = mfma(V^T, P^T) -> ao[b][32][P] f32.
__global__ __launch_bounds__(256, 4)
void attn_mfma_kernel(const short* __restrict__ qT,
                      const short* __restrict__ kT,
                      const short* __restrict__ vT,
                      float* __restrict__ ao) {
    __shared__ unsigned p_lds[4][512];   // per-wave [16 q][64 keys] bf16, swizzled
    __shared__ float o_lds[4][32][16];   // per-wave O^T partial
    __shared__ float m_lds[4][16], l_lds[4][16];

    int blk = blockIdx.x;
    int b = blk >> 8;
    int q0 = (blk & 255) << 4;
    int t = threadIdx.x;
    int w = t >> 6;
    int l = t & 63;
    int lq = l & 15;
    int h = l >> 4;

    const short* qTb = qT + ((size_t)b * P_ + q0) * HD_;
    const short* kTb = kT + (size_t)b * P_ * HD_;
    const short* vb  = vT + (size_t)b * HD_ * P_;

    short8 qf = *(const short8*)(qTb + lq * HD_ + h * 8);

    f32x4 o0 = {0.f, 0.f, 0.f, 0.f}, o1 = {0.f, 0.f, 0.f, 0.f};
    float m = -1e30f, lsum = 0.f;
    unsigned* myp = &p_lds[w][0];
    int swz = (lq & 7) << 4;

    int key_base = w * 1024;
    for (int kt = 0; kt < 16; ++kt) {
        int key0 = key_base + kt * 64;
        f32x4 st[4];
        #pragma unroll
        for (int tt = 0; tt < 4; ++tt) {
            short8 kf = *(const short8*)(kTb + (size_t)(key0 + tt * 16 + lq) * HD_ + h * 8);
            st[tt] = __builtin_amdgcn_mfma_f32_16x16x32_bf16(kf, qf,
                         (f32x4){0.f, 0.f, 0.f, 0.f}, 0, 0, 0);
        }
        float pm = -1e30f;
        #pragma unroll
        for (int tt = 0; tt < 4; ++tt)
            #pragma unroll
            for (int r = 0; r < 4; ++r) pm = fmaxf(pm, st[tt][r]);
        pm *= SCALE_;
        pm = fmaxf(pm, __shfl_xor(pm, 16));
        pm = fmaxf(pm, __shfl_xor(pm, 32));

        float mnew = fmaxf(m, pm);
        float alpha = __expf(m - mnew);
        float rs = 0.f;
        unsigned pk[8];
        #pragma unroll
        for (int tt = 0; tt < 4; ++tt) {
            float p0e = __expf(st[tt][0] * SCALE_ - mnew);
            float p1e = __expf(st[tt][1] * SCALE_ - mnew);
            float p2e = __expf(st[tt][2] * SCALE_ - mnew);
            float p3e = __expf(st[tt][3] * SCALE_ - mnew);
            rs += p0e + p1e + p2e + p3e;
            pk[tt * 2 + 0] = pk_bf16(p0e, p1e);
            pk[tt * 2 + 1] = pk_bf16(p2e, p3e);
        }
        rs += __shfl_xor(rs, 16);
        rs += __shfl_xor(rs, 32);
        lsum = lsum * alpha + rs;
        o0 *= alpha; o1 *= alpha;

        // write P^T tile (bf16 pairs of consecutive keys) to swizzled LDS
        #pragma unroll
        for (int tt = 0; tt < 4; ++tt) {
            int u0 = tt * 32 + h * 8;
            myp[(lq * 128 + ((u0 + 0) ^ swz)) >> 2] = pk[tt * 2 + 0];
            myp[(lq * 128 + ((u0 + 4) ^ swz)) >> 2] = pk[tt * 2 + 1];
        }
        // read PV B-frags (same-wave producer/consumer; no barrier needed)
        short8 pb0, pb1;
        __builtin_memcpy(&pb0, (const char*)myp + lq * 128 + ((h * 16 + 0)  ^ swz), 16);
        __builtin_memcpy(&pb1, (const char*)myp + lq * 128 + ((h * 16 + 64) ^ swz), 16);

        short8 va00 = *(const short8*)(vb + (size_t)(lq)      * P_ + key0 + h * 8);
        short8 va01 = *(const short8*)(vb + (size_t)(lq)      * P_ + key0 + h * 8 + 32);
        short8 va10 = *(const short8*)(vb + (size_t)(16 + lq) * P_ + key0 + h * 8);
        short8 va11 = *(const short8*)(vb + (size_t)(16 + lq) * P_ + key0 + h * 8 + 32);

        o0 = __builtin_amdgcn_mfma_f32_16x16x32_bf16(va00, pb0, o0, 0, 0, 0);
        o0 = __builtin_amdgcn_mfma_f32_16x16x32_bf16(va01, pb1, o0, 0, 0, 0);
        o1 = __builtin_amdgcn_mfma_f32_16x16x32_bf16(va10, pb0, o1, 0, 0, 0);
        o1 = __builtin_amdgcn_mfma_f32_16x16x32_bf16(va11, pb1, o1, 0, 0, 0);
        m = mnew;
    }

    // stash per-wave partials
    #pragma unroll
    for (int r = 0; r < 4; ++r) {
        o_lds[w][h * 4 + r][lq]      = o0[r];
        o_lds[w][16 + h * 4 + r][lq] = o1[r];
    }
    if (h == 0) { m_lds[w][lq] = m; l_lds[w][lq] = lsum; }
    __syncthreads();

    // flash combine across 4 waves; 512 outputs, 2 per thread
    for (int i = t; i < 512; i += 256) {
        int d = i >> 4, qq = i & 15;
        float M = fmaxf(fmaxf(m_lds[0][qq], m_lds[1][qq]),
                        fmaxf(m_lds[2][qq], m_lds[3][qq]));
        float denom = 0.f, val = 0.f;
        #pragma unroll
        for (int ww = 0; ww < 4; ++ww) {
            float f = __expf(m_lds[ww][qq] - M);
            denom += l_lds[ww][qq] * f;
            val   += o_lds[ww][d][qq] * f;
        }
        ao[((size_t)b * HD_ + d) * P_ + q0 + qq] = val / denom;
    }
}

// ---- 3x3 conv (384 out <- 32 in) + bias + residual
__global__ void conv_res_kernel(const float* __restrict__ ao,
                                const float* __restrict__ Wout,
                                const float* __restrict__ bout,
                                const float* __restrict__ x,
                                float* __restrict__ out) {
    int idx = blockIdx.x * 256 + threadIdx.x;
    const int total = B_ * C_ * P_;
    if (idx >= total) return;
    int w = idx & 63;
    int h = (idx >> 6) & 63;
    int co = (idx >> 12) % C_;
    int b = idx / (C_ * P_);
    float acc = bout[co];
    const float* wbase = Wout + (size_t)co * HD_ * 9;
    const float* abase = ao + (size_t)b * HD_ * P_;
    for (int ci = 0; ci < HD_; ++ci) {
        const float* wr = wbase + ci * 9;
        const float* ar = abase + (size_t)ci * P_;
        #pragma unroll
        for (int ky = 0; ky < 3; ++ky) {
            int y = h + ky - 1;
            if ((unsigned)y >= 64u) continue;
            #pragma unroll
            for (int kx = 0; kx < 3; ++kx) {
                int xw = w + kx - 1;
                if ((unsigned)xw >= 64u) continue;
                acc += wr[ky * 3 + kx] * ar[(y << 6) + xw];
            }
        }
    }
    out[idx] = acc + x[idx];
}

extern "C" void kernel_launch(void* const* d_in, const int* in_sizes, int n_in,
                              void* d_out, int out_size, void* d_ws, size_t ws_size,
                              hipStream_t stream) {
    const float* x    = (const float*)d_in[0];
    const float* xe   = (const float*)d_in[1];
    const float* Wq   = (const float*)d_in[2];
    const float* Wkv  = (const float*)d_in[3];
    const float* Wout = (const float*)d_in[4];
    const float* bout = (const float*)d_in[5];
    float* out = (float*)d_out;

    short* qT = (short*)d_ws;                       // B*P*32 bf16
    short* kT = qT + (size_t)B_ * P_ * HD_;         // B*P*32 bf16
    short* vT = kT + (size_t)B_ * P_ * HD_;         // B*32*P bf16
    float* ao = (float*)(vT + (size_t)B_ * P_ * HD_); // B*32*P f32

    proj_q_kernel <<<B_ * 64, 256, 0, stream>>>(Wq, x, qT);
    proj_kv_kernel<<<B_ * 64, 256, 0, stream>>>(Wkv, xe, kT, vT);
    attn_mfma_kernel<<<B_ * 256, 256, 0, stream>>>(qT, kT, vT, ao);
    {
        int total = B_ * C_ * P_;
        conv_res_kernel<<<(total + 255) / 256, 256, 0, stream>>>(ao, Wout, bout, x, out);
    }
}

// Round 3
// 142.586 us; speedup vs baseline: 13.2879x; 4.2996x over previous
//
#include <hip/hip_runtime.h>
#include <hip/hip_bf16.h>
#include <math.h>

// B=4, C=384, H=W=Y=X=64, n_head=1, hd=32, P=4096
#define B_   4
#define C_   384
#define HD_  32
#define P_   4096
#define PADP 4356   // 66*66 padded pixel space
#define SCALE_ 0.17677669529663687f  // 1/sqrt(32)

typedef __attribute__((ext_vector_type(4))) float f32x4;
typedef __attribute__((ext_vector_type(8))) short short8;

static __device__ inline unsigned pk_bf16(float a, float b) {
    __hip_bfloat16 x = __float2bfloat16(a), y = __float2bfloat16(b);
    unsigned short ux = *reinterpret_cast<unsigned short*>(&x);
    unsigned short uy = *reinterpret_cast<unsigned short*>(&y);
    return (unsigned)ux | ((unsigned)uy << 16);
}
static __device__ inline short bf16_bits(float a) {
    __hip_bfloat16 x = __float2bfloat16(a);
    return *reinterpret_cast<short*>(&x);
}

__global__ void zero_kernel(f32x4* __restrict__ p, int n16) {
    int i = blockIdx.x * 256 + threadIdx.x;
    if (i < n16) p[i] = (f32x4){0.f, 0.f, 0.f, 0.f};
}

// Wb[(ky*3+kx)*384 + co][ci] bf16 <- Wout[co][ci][ky][kx] f32
__global__ void repack_w_kernel(const float* __restrict__ Wout,
                                short* __restrict__ Wb) {
    int idx = blockIdx.x * 256 + threadIdx.x;
    if (idx >= 9 * 384 * 32) return;
    int ci = idx & 31;
    int co = (idx >> 5) % 384;
    int kk = idx / (384 * 32);
    int ky = kk / 3, kx = kk % 3;
    Wb[idx] = bf16_bits(Wout[((co * 32 + ci) * 3 + ky) * 3 + kx]);
}

// ---- Q projection: qT[b][p][32] bf16 = Wq[32][384] . x[b][384][p]
__global__ void proj_q_kernel(const float* __restrict__ Wq,
                              const float* __restrict__ x,
                              short* __restrict__ qT) {
    __shared__ float xs[64][64];
    __shared__ float ws[32][64];
    int b  = blockIdx.x >> 6;
    int p0 = (blockIdx.x & 63) << 6;
    int t = threadIdx.x;
    int p = t & 63, dg = t >> 6;
    float acc[8] = {0,0,0,0,0,0,0,0};
    for (int c0 = 0; c0 < C_; c0 += 64) {
        __syncthreads();
        #pragma unroll
        for (int i = 0; i < 16; ++i) {
            int row = (t >> 6) + i * 4;
            xs[row][p] = x[((size_t)b * C_ + c0 + row) * P_ + p0 + p];
        }
        #pragma unroll
        for (int i = 0; i < 8; ++i) {
            int idx = t + i * 256;
            int d = idx >> 6, cc = idx & 63;
            ws[d][cc] = Wq[(size_t)d * C_ + c0 + cc];
        }
        __syncthreads();
        for (int cc = 0; cc < 64; ++cc) {
            float xv = xs[cc][p];
            #pragma unroll
            for (int j = 0; j < 8; ++j) acc[j] += ws[dg * 8 + j][cc] * xv;
        }
    }
    unsigned* outp = (unsigned*)(qT + ((size_t)b * P_ + p0 + p) * HD_ + dg * 8);
    #pragma unroll
    for (int j = 0; j < 4; ++j) outp[j] = pk_bf16(acc[2 * j], acc[2 * j + 1]);
}

// ---- KV projection: kT[b][p][32] bf16 (d 0..31), vT[b][32][p] bf16 (d 32..63)
__global__ void proj_kv_kernel(const float* __restrict__ Wkv,
                               const float* __restrict__ xe,
                               short* __restrict__ kT,
                               short* __restrict__ vT) {
    __shared__ float xs[64][64];
    __shared__ float ws[64][64];
    int b  = blockIdx.x >> 6;
    int p0 = (blockIdx.x & 63) << 6;
    int t = threadIdx.x;
    int p = t & 63, dg = t >> 6;
    float acc[16];
    #pragma unroll
    for (int j = 0; j < 16; ++j) acc[j] = 0.f;
    for (int c0 = 0; c0 < C_; c0 += 64) {
        __syncthreads();
        #pragma unroll
        for (int i = 0; i < 16; ++i) {
            int row = (t >> 6) + i * 4;
            xs[row][p] = xe[((size_t)b * C_ + c0 + row) * P_ + p0 + p];
        }
        #pragma unroll
        for (int i = 0; i < 16; ++i) {
            int idx = t + i * 256;
            int d = idx >> 6, cc = idx & 63;
            ws[d][cc] = Wkv[(size_t)d * C_ + c0 + cc];
        }
        __syncthreads();
        for (int cc = 0; cc < 64; ++cc) {
            float xv = xs[cc][p];
            #pragma unroll
            for (int j = 0; j < 16; ++j) acc[j] += ws[dg * 16 + j][cc] * xv;
        }
    }
    if (dg < 2) {
        unsigned* outp = (unsigned*)(kT + ((size_t)b * P_ + p0 + p) * HD_ + dg * 16);
        #pragma unroll
        for (int j = 0; j < 8; ++j) outp[j] = pk_bf16(acc[2 * j], acc[2 * j + 1]);
    } else {
        #pragma unroll
        for (int j = 0; j < 16; ++j) {
            int d = (dg - 2) * 16 + j;
            vT[((size_t)b * HD_ + d) * P_ + p0 + p] = bf16_bits(acc[j]);
        }
    }
}

// ---- Flash attention, MFMA. Grid: B*(P/16) blocks, 256 threads (4 waves).
// Epilogue writes aoT[b][(h+1)*66+(w+1)][32] bf16 (padded pixel-major).
__global__ __launch_bounds__(256, 4)
void attn_mfma_kernel(const short* __restrict__ qT,
                      const short* __restrict__ kT,
                      const short* __restrict__ vT,
                      short* __restrict__ aoT) {
    __shared__ unsigned p_lds[4][512];
    __shared__ float o_lds[4][32][16];
    __shared__ float m_lds[4][16], l_lds[4][16];

    int blk = blockIdx.x;
    int b = blk >> 8;
    int q0 = (blk & 255) << 4;
    int t = threadIdx.x;
    int w = t >> 6;
    int l = t & 63;
    int lq = l & 15;
    int h = l >> 4;

    const short* qTb = qT + ((size_t)b * P_ + q0) * HD_;
    const short* kTb = kT + (size_t)b * P_ * HD_;
    const short* vb  = vT + (size_t)b * HD_ * P_;

    short8 qf = *(const short8*)(qTb + lq * HD_ + h * 8);

    f32x4 o0 = {0.f, 0.f, 0.f, 0.f}, o1 = {0.f, 0.f, 0.f, 0.f};
    float m = -1e30f, lsum = 0.f;
    unsigned* myp = &p_lds[w][0];
    int swz = (lq & 7) << 4;

    int key_base = w * 1024;
    for (int kt = 0; kt < 16; ++kt) {
        int key0 = key_base + kt * 64;
        f32x4 st[4];
        #pragma unroll
        for (int tt = 0; tt < 4; ++tt) {
            short8 kf = *(const short8*)(kTb + (size_t)(key0 + tt * 16 + lq) * HD_ + h * 8);
            st[tt] = __builtin_amdgcn_mfma_f32_16x16x32_bf16(kf, qf,
                         (f32x4){0.f, 0.f, 0.f, 0.f}, 0, 0, 0);
        }
        float pm = -1e30f;
        #pragma unroll
        for (int tt = 0; tt < 4; ++tt)
            #pragma unroll
            for (int r = 0; r < 4; ++r) pm = fmaxf(pm, st[tt][r]);
        pm *= SCALE_;
        pm = fmaxf(pm, __shfl_xor(pm, 16));
        pm = fmaxf(pm, __shfl_xor(pm, 32));

        float mnew = fmaxf(m, pm);
        float alpha = __expf(m - mnew);
        float rs = 0.f;
        unsigned pk[8];
        #pragma unroll
        for (int tt = 0; tt < 4; ++tt) {
            float p0e = __expf(st[tt][0] * SCALE_ - mnew);
            float p1e = __expf(st[tt][1] * SCALE_ - mnew);
            float p2e = __expf(st[tt][2] * SCALE_ - mnew);
            float p3e = __expf(st[tt][3] * SCALE_ - mnew);
            rs += p0e + p1e + p2e + p3e;
            pk[tt * 2 + 0] = pk_bf16(p0e, p1e);
            pk[tt * 2 + 1] = pk_bf16(p2e, p3e);
        }
        rs += __shfl_xor(rs, 16);
        rs += __shfl_xor(rs, 32);
        lsum = lsum * alpha + rs;
        o0 *= alpha; o1 *= alpha;

        #pragma unroll
        for (int tt = 0; tt < 4; ++tt) {
            int u0 = tt * 32 + h * 8;
            myp[(lq * 128 + ((u0 + 0) ^ swz)) >> 2] = pk[tt * 2 + 0];
            myp[(lq * 128 + ((u0 + 4) ^ swz)) >> 2] = pk[tt * 2 + 1];
        }
        short8 pb0, pb1;
        __builtin_memcpy(&pb0, (const char*)myp + lq * 128 + ((h * 16 + 0)  ^ swz), 16);
        __builtin_memcpy(&pb1, (const char*)myp + lq * 128 + ((h * 16 + 64) ^ swz), 16);

        short8 va00 = *(const short8*)(vb + (size_t)(lq)      * P_ + key0 + h * 8);
        short8 va01 = *(const short8*)(vb + (size_t)(lq)      * P_ + key0 + h * 8 + 32);
        short8 va10 = *(const short8*)(vb + (size_t)(16 + lq) * P_ + key0 + h * 8);
        short8 va11 = *(const short8*)(vb + (size_t)(16 + lq) * P_ + key0 + h * 8 + 32);

        o0 = __builtin_amdgcn_mfma_f32_16x16x32_bf16(va00, pb0, o0, 0, 0, 0);
        o0 = __builtin_amdgcn_mfma_f32_16x16x32_bf16(va01, pb1, o0, 0, 0, 0);
        o1 = __builtin_amdgcn_mfma_f32_16x16x32_bf16(va10, pb0, o1, 0, 0, 0);
        o1 = __builtin_amdgcn_mfma_f32_16x16x32_bf16(va11, pb1, o1, 0, 0, 0);
        m = mnew;
    }

    #pragma unroll
    for (int r = 0; r < 4; ++r) {
        o_lds[w][h * 4 + r][lq]      = o0[r];
        o_lds[w][16 + h * 4 + r][lq] = o1[r];
    }
    if (h == 0) { m_lds[w][lq] = m; l_lds[w][lq] = lsum; }
    __syncthreads();

    // combine: 512 outputs = 16 q x 16 d-pairs; thread t: qq=t>>4, d0=(t&15)*2
    {
        int qq = t >> 4;
        int d0 = (t & 15) * 2;
        float M = fmaxf(fmaxf(m_lds[0][qq], m_lds[1][qq]),
                        fmaxf(m_lds[2][qq], m_lds[3][qq]));
        float f[4]; float denom = 0.f;
        #pragma unroll
        for (int ww = 0; ww < 4; ++ww) {
            f[ww] = __expf(m_lds[ww][qq] - M);
            denom += l_lds[ww][qq] * f[ww];
        }
        float inv = 1.f / denom;
        float v0 = 0.f, v1 = 0.f;
        #pragma unroll
        for (int ww = 0; ww < 4; ++ww) {
            v0 += o_lds[ww][d0][qq] * f[ww];
            v1 += o_lds[ww][d0 + 1][qq] * f[ww];
        }
        int p = q0 + qq;
        int hh = p >> 6, ww2 = p & 63;
        unsigned* dst = (unsigned*)(aoT +
            ((size_t)b * PADP + (hh + 1) * 66 + (ww2 + 1)) * HD_ + d0);
        *dst = pk_bf16(v0 * inv, v1 * inv);
    }
}

// ---- Conv as implicit GEMM: out[b][co][p] = sum_{kk,ci} Wb[kk][co][ci]*aoT[b][pix+off(kk)][ci]
// Grid: B_*128 blocks (32-pixel tiles), 256 threads (4 waves), wave w: co [w*96, w*96+96)
__global__ __launch_bounds__(256)
void conv_mfma_kernel(const short* __restrict__ Wb,
                      const short* __restrict__ aoT,
                      const float* __restrict__ bout,
                      const float* __restrict__ x,
                      float* __restrict__ out) {
    int blk = blockIdx.x;
    int b = blk >> 7;
    int p0 = (blk & 127) << 5;
    int t = threadIdx.x;
    int w = t >> 6, l = t & 63, lq = l & 15, h = l >> 4;
    int co0 = w * 96;

    const short* aob = aoT + (size_t)b * PADP * HD_;
    const short* bptr[2];
    #pragma unroll
    for (int n = 0; n < 2; ++n) {
        int p = p0 + n * 16 + lq;
        int hh = p >> 6, ww = p & 63;
        bptr[n] = aob + (size_t)(hh * 66 + ww) * HD_ + h * 8;
    }
    const short* aptr = Wb + (size_t)(co0 + lq) * 32 + h * 8;

    f32x4 acc[6][2];
    #pragma unroll
    for (int m = 0; m < 6; ++m)
        #pragma unroll
        for (int n = 0; n < 2; ++n) acc[m][n] = (f32x4){0.f, 0.f, 0.f, 0.f};

    #pragma unroll
    for (int ky = 0; ky < 3; ++ky) {
        #pragma unroll
        for (int kx = 0; kx < 3; ++kx) {
            int kk = ky * 3 + kx;
            short8 Bf[2];
            #pragma unroll
            for (int n = 0; n < 2; ++n)
                Bf[n] = *(const short8*)(bptr[n] + (ky * 66 + kx) * HD_);
            #pragma unroll
            for (int m = 0; m < 6; ++m) {
                short8 Af = *(const short8*)(aptr + kk * 12288 + m * 512);
                #pragma unroll
                for (int n = 0; n < 2; ++n)
                    acc[m][n] = __builtin_amdgcn_mfma_f32_16x16x32_bf16(
                                    Af, Bf[n], acc[m][n], 0, 0, 0);
            }
        }
    }

    #pragma unroll
    for (int m = 0; m < 6; ++m) {
        #pragma unroll
        for (int r = 0; r < 4; ++r) {
            int co = co0 + m * 16 + h * 4 + r;
            float bias = bout[co];
            #pragma unroll
            for (int n = 0; n < 2; ++n) {
                int p = p0 + n * 16 + lq;
                size_t idx = ((size_t)b * C_ + co) * P_ + p;
                out[idx] = acc[m][n][r] + bias + x[idx];
            }
        }
    }
}

extern "C" void kernel_launch(void* const* d_in, const int* in_sizes, int n_in,
                              void* d_out, int out_size, void* d_ws, size_t ws_size,
                              hipStream_t stream) {
    const float* x    = (const float*)d_in[0];
    const float* xe   = (const float*)d_in[1];
    const float* Wq   = (const float*)d_in[2];
    const float* Wkv  = (const float*)d_in[3];
    const float* Wout = (const float*)d_in[4];
    const float* bout = (const float*)d_in[5];
    float* out = (float*)d_out;

    short* qT  = (short*)d_ws;                        // B*P*32
    short* kT  = qT + (size_t)B_ * P_ * HD_;          // B*P*32
    short* vT  = kT + (size_t)B_ * P_ * HD_;          // B*32*P
    short* aoT = vT + (size_t)B_ * P_ * HD_;          // B*PADP*32
    short* Wb  = aoT + (size_t)B_ * PADP * HD_;       // 9*384*32

    {   // zero padded attn-out buffer (border must be 0)
        int n16 = (B_ * PADP * HD_ * 2) / 16;         // 69696
        zero_kernel<<<(n16 + 255) / 256, 256, 0, stream>>>((f32x4*)aoT, n16);
    }
    repack_w_kernel<<<(9 * 384 * 32 + 255) / 256, 256, 0, stream>>>(Wout, Wb);
    proj_q_kernel <<<B_ * 64, 256, 0, stream>>>(Wq, x, qT);
    proj_kv_kernel<<<B_ * 64, 256, 0, stream>>>(Wkv, xe, kT, vT);
    attn_mfma_kernel<<<B_ * 256, 256, 0, stream>>>(qT, kT, vT, aoT);
    conv_mfma_kernel<<<B_ * 128, 256, 0, stream>>>(Wb, aoT, bout, x, out);
}

// Round 4
// 108.351 us; speedup vs baseline: 17.4864x; 1.3160x over previous
//
#include <hip/hip_runtime.h>
#include <hip/hip_bf16.h>
#include <math.h>

// B=4, C=384, H=W=Y=X=64, n_head=1, hd=32, P=4096
#define B_   4
#define C_   384
#define HD_  32
#define P_   4096
#define PADP 4356   // 66*66 padded pixel space
#define SCALE_ 0.17677669529663687f  // 1/sqrt(32)

typedef __attribute__((ext_vector_type(4))) float f32x4;
typedef __attribute__((ext_vector_type(8))) short short8;

static __device__ inline unsigned pk_bf16(float a, float b) {
    __hip_bfloat16 x = __float2bfloat16(a), y = __float2bfloat16(b);
    unsigned short ux = *reinterpret_cast<unsigned short*>(&x);
    unsigned short uy = *reinterpret_cast<unsigned short*>(&y);
    return (unsigned)ux | ((unsigned)uy << 16);
}
static __device__ inline short bf16_bits(float a) {
    __hip_bfloat16 x = __float2bfloat16(a);
    return *reinterpret_cast<short*>(&x);
}

__global__ void zero_kernel(f32x4* __restrict__ p, int n16) {
    int i = blockIdx.x * 256 + threadIdx.x;
    if (i < n16) p[i] = (f32x4){0.f, 0.f, 0.f, 0.f};
}

// Wball[96][384] bf16: rows 0-31 = Wq, rows 32-95 = Wkv
__global__ void repack_wproj_kernel(const float* __restrict__ Wq,
                                    const float* __restrict__ Wkv,
                                    short* __restrict__ Wball) {
    int idx = blockIdx.x * 256 + threadIdx.x;
    if (idx >= 96 * C_) return;
    int r = idx / C_, c = idx % C_;
    float v = (r < 32) ? Wq[r * C_ + c] : Wkv[(r - 32) * C_ + c];
    Wball[idx] = bf16_bits(v);
}

// Wbc[(ky*3+kx)*384 + co][ci] bf16 <- Wout[co][ci][ky][kx] f32
__global__ void repack_wconv_kernel(const float* __restrict__ Wout,
                                    short* __restrict__ Wbc) {
    int idx = blockIdx.x * 256 + threadIdx.x;
    if (idx >= 9 * 384 * 32) return;
    int ci = idx & 31;
    int co = (idx >> 5) % 384;
    int kk = idx / (384 * 32);
    int ky = kk / 3, kx = kk % 3;
    Wbc[idx] = bf16_bits(Wout[((co * 32 + ci) * 3 + ky) * 3 + kx]);
}

// ---- transpose-convert: outT[b][p][c] bf16 <- in[b][c][p] f32
// grid: (384, B): blockIdx.x = ct*64 + pt (64x64 tiles)
__global__ __launch_bounds__(256)
void transpose_kernel(const float* __restrict__ in, short* __restrict__ outT) {
    __shared__ float ls[64][65];
    int ct = blockIdx.x >> 6;     // 0..5
    int pt = blockIdx.x & 63;     // 0..63
    int b  = blockIdx.y;
    int c0 = ct << 6, p0 = pt << 6;
    int t = threadIdx.x;
    {
        int cc = t >> 2, pb = (t & 3) << 4;
        const float* src = in + ((size_t)b * C_ + c0 + cc) * P_ + p0 + pb;
        float4 v0 = *(const float4*)(src);
        float4 v1 = *(const float4*)(src + 4);
        float4 v2 = *(const float4*)(src + 8);
        float4 v3 = *(const float4*)(src + 12);
        float* d = &ls[cc][pb];
        d[0]=v0.x; d[1]=v0.y; d[2]=v0.z; d[3]=v0.w;
        d[4]=v1.x; d[5]=v1.y; d[6]=v1.z; d[7]=v1.w;
        d[8]=v2.x; d[9]=v2.y; d[10]=v2.z; d[11]=v2.w;
        d[12]=v3.x; d[13]=v3.y; d[14]=v3.z; d[15]=v3.w;
    }
    __syncthreads();
    {
        int p = t >> 2, cb = (t & 3) << 4;
        unsigned pkv[8];
        #pragma unroll
        for (int j = 0; j < 8; ++j)
            pkv[j] = pk_bf16(ls[cb + 2 * j][p], ls[cb + 2 * j + 1][p]);
        unsigned* dst = (unsigned*)(outT + ((size_t)b * P_ + p0 + p) * C_ + c0 + cb);
        #pragma unroll
        for (int j = 0; j < 8; ++j) dst[j] = pkv[j];
    }
}

// ---- projection GEMM: M=32 (one role), K=384, N=64 pixels per block.
// role = role0 + blockIdx.z: 0=q (out pmOut[p][32]), 1=k (pmOut), 2=v (vOut[d][P])
// grid: (64, B, nroles), 256 threads (4 waves, wave = 16 pixels)
__global__ __launch_bounds__(256)
void proj_gemm_kernel(const short* __restrict__ inT, const short* __restrict__ Wball,
                      short* __restrict__ pmOut, short* __restrict__ vOut, int role0) {
    int role = role0 + blockIdx.z;
    int b = blockIdx.y;
    int p0 = blockIdx.x << 6;
    int t = threadIdx.x, w = t >> 6, l = t & 63, lq = l & 15, h = l >> 4;
    int p = p0 + w * 16 + lq;
    const short* Ap = Wball + (size_t)(role * 32 + lq) * C_ + h * 8;
    const short* Bp = inT + ((size_t)b * P_ + p) * C_ + h * 8;
    f32x4 acc0 = {0.f,0.f,0.f,0.f}, acc1 = {0.f,0.f,0.f,0.f};
    short8 a0 = *(const short8*)(Ap);
    short8 a1 = *(const short8*)(Ap + 16 * C_);
    short8 bb = *(const short8*)(Bp);
    #pragma unroll
    for (int ks = 0; ks < 11; ++ks) {
        const short* Ap2 = Ap + (ks + 1) * 32;
        short8 na0 = *(const short8*)(Ap2);
        short8 na1 = *(const short8*)(Ap2 + 16 * C_);
        short8 nbb = *(const short8*)(Bp + (ks + 1) * 32);
        acc0 = __builtin_amdgcn_mfma_f32_16x16x32_bf16(a0, bb, acc0, 0, 0, 0);
        acc1 = __builtin_amdgcn_mfma_f32_16x16x32_bf16(a1, bb, acc1, 0, 0, 0);
        a0 = na0; a1 = na1; bb = nbb;
    }
    acc0 = __builtin_amdgcn_mfma_f32_16x16x32_bf16(a0, bb, acc0, 0, 0, 0);
    acc1 = __builtin_amdgcn_mfma_f32_16x16x32_bf16(a1, bb, acc1, 0, 0, 0);

    if (role < 2) {
        uint2 u0, u1;
        u0.x = pk_bf16(acc0[0], acc0[1]); u0.y = pk_bf16(acc0[2], acc0[3]);
        u1.x = pk_bf16(acc1[0], acc1[1]); u1.y = pk_bf16(acc1[2], acc1[3]);
        *(uint2*)(pmOut + ((size_t)b * P_ + p) * HD_ + h * 4)      = u0;
        *(uint2*)(pmOut + ((size_t)b * P_ + p) * HD_ + 16 + h * 4) = u1;
    } else {
        #pragma unroll
        for (int r = 0; r < 4; ++r) {
            vOut[((size_t)b * HD_ + h * 4 + r) * P_ + p]      = bf16_bits(acc0[r]);
            vOut[((size_t)b * HD_ + 16 + h * 4 + r) * P_ + p] = bf16_bits(acc1[r]);
        }
    }
}

// ---- Flash attention, MFMA, reg-prefetch K/V, setprio, defer-max.
__global__ __launch_bounds__(256, 4)
void attn_mfma_kernel(const short* __restrict__ qT,
                      const short* __restrict__ kT,
                      const short* __restrict__ vT,
                      short* __restrict__ aoT) {
    __shared__ unsigned p_lds[4][512];
    __shared__ float o_lds[4][32][16];
    __shared__ float m_lds[4][16], l_lds[4][16];

    int blk = blockIdx.x;
    int b = blk >> 8;
    int q0 = (blk & 255) << 4;
    int t = threadIdx.x;
    int w = t >> 6;
    int l = t & 63;
    int lq = l & 15;
    int h = l >> 4;

    const short* qTb = qT + ((size_t)b * P_ + q0) * HD_;
    const short* kTb = kT + (size_t)b * P_ * HD_;
    const short* vb  = vT + (size_t)b * HD_ * P_;

    short8 qf = *(const short8*)(qTb + lq * HD_ + h * 8);

    f32x4 o0 = {0.f,0.f,0.f,0.f}, o1 = {0.f,0.f,0.f,0.f};
    float m = -1e30f, lsum = 0.f;
    unsigned* myp = &p_lds[w][0];
    int swz = (lq & 7) << 4;

    int key_base = w * 1024;
    short8 kf[4], vf[4];
    {
        const short* kp = kTb + (size_t)(key_base + lq) * HD_ + h * 8;
        #pragma unroll
        for (int tt = 0; tt < 4; ++tt) kf[tt] = *(const short8*)(kp + tt * 16 * HD_);
        const short* vp = vb + (size_t)lq * P_ + key_base + h * 8;
        vf[0] = *(const short8*)(vp);
        vf[1] = *(const short8*)(vp + 32);
        vf[2] = *(const short8*)(vp + 16 * P_);
        vf[3] = *(const short8*)(vp + 16 * P_ + 32);
    }

    for (int kt = 0; kt < 16; ++kt) {
        short8 nk[4], nv[4];
        if (kt < 15) {
            int nxt = key_base + (kt + 1) * 64;
            const short* kp = kTb + (size_t)(nxt + lq) * HD_ + h * 8;
            #pragma unroll
            for (int tt = 0; tt < 4; ++tt) nk[tt] = *(const short8*)(kp + tt * 16 * HD_);
            const short* vp = vb + (size_t)lq * P_ + nxt + h * 8;
            nv[0] = *(const short8*)(vp);
            nv[1] = *(const short8*)(vp + 32);
            nv[2] = *(const short8*)(vp + 16 * P_);
            nv[3] = *(const short8*)(vp + 16 * P_ + 32);
        } else {
            #pragma unroll
            for (int tt = 0; tt < 4; ++tt) { nk[tt] = kf[tt]; nv[tt] = vf[tt]; }
        }

        f32x4 st[4];
        __builtin_amdgcn_s_setprio(1);
        #pragma unroll
        for (int tt = 0; tt < 4; ++tt)
            st[tt] = __builtin_amdgcn_mfma_f32_16x16x32_bf16(kf[tt], qf,
                         (f32x4){0.f,0.f,0.f,0.f}, 0, 0, 0);
        __builtin_amdgcn_s_setprio(0);

        float pm = -1e30f;
        #pragma unroll
        for (int tt = 0; tt < 4; ++tt)
            #pragma unroll
            for (int r = 0; r < 4; ++r) pm = fmaxf(pm, st[tt][r]);
        pm *= SCALE_;
        pm = fmaxf(pm, __shfl_xor(pm, 16));
        pm = fmaxf(pm, __shfl_xor(pm, 32));

        bool skip = __all(pm - m <= 8.0f);
        if (!skip) {
            float mnew = fmaxf(m, pm);
            float alpha = __expf(m - mnew);
            o0 *= alpha; o1 *= alpha;
            lsum *= alpha;
            m = mnew;
        }

        float rs = 0.f;
        unsigned pk[8];
        #pragma unroll
        for (int tt = 0; tt < 4; ++tt) {
            float p0e = __expf(st[tt][0] * SCALE_ - m);
            float p1e = __expf(st[tt][1] * SCALE_ - m);
            float p2e = __expf(st[tt][2] * SCALE_ - m);
            float p3e = __expf(st[tt][3] * SCALE_ - m);
            rs += p0e + p1e + p2e + p3e;
            pk[tt * 2 + 0] = pk_bf16(p0e, p1e);
            pk[tt * 2 + 1] = pk_bf16(p2e, p3e);
        }
        rs += __shfl_xor(rs, 16);
        rs += __shfl_xor(rs, 32);
        lsum += rs;

        #pragma unroll
        for (int tt = 0; tt < 4; ++tt) {
            int u0 = tt * 32 + h * 8;
            myp[(lq * 128 + ((u0 + 0) ^ swz)) >> 2] = pk[tt * 2 + 0];
            myp[(lq * 128 + ((u0 + 4) ^ swz)) >> 2] = pk[tt * 2 + 1];
        }
        short8 pb0, pb1;
        __builtin_memcpy(&pb0, (const char*)myp + lq * 128 + ((h * 16 + 0)  ^ swz), 16);
        __builtin_memcpy(&pb1, (const char*)myp + lq * 128 + ((h * 16 + 64) ^ swz), 16);

        __builtin_amdgcn_s_setprio(1);
        o0 = __builtin_amdgcn_mfma_f32_16x16x32_bf16(vf[0], pb0, o0, 0, 0, 0);
        o0 = __builtin_amdgcn_mfma_f32_16x16x32_bf16(vf[1], pb1, o0, 0, 0, 0);
        o1 = __builtin_amdgcn_mfma_f32_16x16x32_bf16(vf[2], pb0, o1, 0, 0, 0);
        o1 = __builtin_amdgcn_mfma_f32_16x16x32_bf16(vf[3], pb1, o1, 0, 0, 0);
        __builtin_amdgcn_s_setprio(0);

        #pragma unroll
        for (int tt = 0; tt < 4; ++tt) { kf[tt] = nk[tt]; vf[tt] = nv[tt]; }
    }

    #pragma unroll
    for (int r = 0; r < 4; ++r) {
        o_lds[w][h * 4 + r][lq]      = o0[r];
        o_lds[w][16 + h * 4 + r][lq] = o1[r];
    }
    if (h == 0) { m_lds[w][lq] = m; l_lds[w][lq] = lsum; }
    __syncthreads();

    {
        int qq = t >> 4;
        int d0 = (t & 15) * 2;
        float M = fmaxf(fmaxf(m_lds[0][qq], m_lds[1][qq]),
                        fmaxf(m_lds[2][qq], m_lds[3][qq]));
        float f[4]; float denom = 0.f;
        #pragma unroll
        for (int ww = 0; ww < 4; ++ww) {
            f[ww] = __expf(m_lds[ww][qq] - M);
            denom += l_lds[ww][qq] * f[ww];
        }
        float inv = 1.f / denom;
        float v0 = 0.f, v1 = 0.f;
        #pragma unroll
        for (int ww = 0; ww < 4; ++ww) {
            v0 += o_lds[ww][d0][qq] * f[ww];
            v1 += o_lds[ww][d0 + 1][qq] * f[ww];
        }
        int p = q0 + qq;
        int hh = p >> 6, ww2 = p & 63;
        unsigned* dst = (unsigned*)(aoT +
            ((size_t)b * PADP + (hh + 1) * 66 + (ww2 + 1)) * HD_ + d0);
        *dst = pk_bf16(v0 * inv, v1 * inv);
    }
}

// ---- Conv implicit GEMM: 512 threads (8 waves), wave w: co [w*48, w*48+48), 32-pixel tile
__global__ __launch_bounds__(512)
void conv_mfma_kernel(const short* __restrict__ Wbc,
                      const short* __restrict__ aoT,
                      const float* __restrict__ bout,
                      const float* __restrict__ x,
                      float* __restrict__ out) {
    int blk = blockIdx.x;
    int b = blk >> 7;
    int p0 = (blk & 127) << 5;
    int t = threadIdx.x;
    int w = t >> 6, l = t & 63, lq = l & 15, h = l >> 4;
    int co0 = w * 48;

    const short* aob = aoT + (size_t)b * PADP * HD_;
    const short* bptr[2];
    #pragma unroll
    for (int n = 0; n < 2; ++n) {
        int p = p0 + n * 16 + lq;
        int hh = p >> 6, ww = p & 63;
        bptr[n] = aob + (size_t)(hh * 66 + ww) * HD_ + h * 8;
    }
    const short* aptr = Wbc + (size_t)(co0 + lq) * 32 + h * 8;

    f32x4 acc[3][2];
    #pragma unroll
    for (int m = 0; m < 3; ++m)
        #pragma unroll
        for (int n = 0; n < 2; ++n) acc[m][n] = (f32x4){0.f,0.f,0.f,0.f};

    short8 Bf0 = *(const short8*)(bptr[0]);
    short8 Bf1 = *(const short8*)(bptr[1]);
    #pragma unroll
    for (int kk = 0; kk < 9; ++kk) {
        short8 nB0, nB1;
        if (kk < 8) {
            int ky = (kk + 1) / 3, kx = (kk + 1) % 3;
            nB0 = *(const short8*)(bptr[0] + (ky * 66 + kx) * HD_);
            nB1 = *(const short8*)(bptr[1] + (ky * 66 + kx) * HD_);
        } else { nB0 = Bf0; nB1 = Bf1; }
        #pragma unroll
        for (int m = 0; m < 3; ++m) {
            short8 Af = *(const short8*)(aptr + kk * 12288 + m * 512);
            acc[m][0] = __builtin_amdgcn_mfma_f32_16x16x32_bf16(Af, Bf0, acc[m][0], 0, 0, 0);
            acc[m][1] = __builtin_amdgcn_mfma_f32_16x16x32_bf16(Af, Bf1, acc[m][1], 0, 0, 0);
        }
        Bf0 = nB0; Bf1 = nB1;
    }

    #pragma unroll
    for (int m = 0; m < 3; ++m) {
        #pragma unroll
        for (int r = 0; r < 4; ++r) {
            int co = co0 + m * 16 + h * 4 + r;
            float bias = bout[co];
            #pragma unroll
            for (int n = 0; n < 2; ++n) {
                int p = p0 + n * 16 + lq;
                size_t idx = ((size_t)b * C_ + co) * P_ + p;
                out[idx] = acc[m][n][r] + bias + x[idx];
            }
        }
    }
}

extern "C" void kernel_launch(void* const* d_in, const int* in_sizes, int n_in,
                              void* d_out, int out_size, void* d_ws, size_t ws_size,
                              hipStream_t stream) {
    const float* x    = (const float*)d_in[0];
    const float* xe   = (const float*)d_in[1];
    const float* Wq   = (const float*)d_in[2];
    const float* Wkv  = (const float*)d_in[3];
    const float* Wout = (const float*)d_in[4];
    const float* bout = (const float*)d_in[5];
    float* out = (float*)d_out;

    short* iT    = (short*)d_ws;                         // B*P*384 (shared x/xe transpose)
    short* qT    = iT    + (size_t)B_ * P_ * C_;         // B*P*32
    short* kT    = qT    + (size_t)B_ * P_ * HD_;        // B*P*32
    short* vT    = kT    + (size_t)B_ * P_ * HD_;        // B*32*P
    short* aoT   = vT    + (size_t)B_ * P_ * HD_;        // B*PADP*32
    short* Wball = aoT   + (size_t)B_ * PADP * HD_;      // 96*384
    short* Wbc   = Wball + 96 * C_;                      // 9*384*32

    {   // zero padded attn-out buffer (border must be 0)
        int n16 = (B_ * PADP * HD_ * 2) / 16;            // 69696
        zero_kernel<<<(n16 + 255) / 256, 256, 0, stream>>>((f32x4*)aoT, n16);
    }
    repack_wproj_kernel<<<(96 * C_ + 255) / 256, 256, 0, stream>>>(Wq, Wkv, Wball);
    repack_wconv_kernel<<<(9 * 384 * 32 + 255) / 256, 256, 0, stream>>>(Wout, Wbc);

    // xe -> iT, then k+v projections (roles 1,2)
    transpose_kernel<<<dim3(384, B_), 256, 0, stream>>>(xe, iT);
    proj_gemm_kernel<<<dim3(64, B_, 2), 256, 0, stream>>>(iT, Wball, kT, vT, 1);
    // x -> iT (reuse), then q projection (role 0)
    transpose_kernel<<<dim3(384, B_), 256, 0, stream>>>(x, iT);
    proj_gemm_kernel<<<dim3(64, B_, 1), 256, 0, stream>>>(iT, Wball, qT, vT, 0);

    attn_mfma_kernel<<<B_ * 256, 256, 0, stream>>>(qT, kT, vT, aoT);
    conv_mfma_kernel<<<B_ * 128, 512, 0, stream>>>(Wbc, aoT, bout, x, out);
}